// Round 3
// baseline (733.263 us; speedup 1.0000x reference)
//
#include <hip/hip_runtime.h>

#define B_    1024
#define N_    100000
#define NP_   100096   // N padded to multiple of 64 (n-tile)
#define NR_   500
#define D_    200
#define KP_   224      // D padded to multiple of 32 (MFMA K)
#define OC_   32
#define FW_   9
#define L_    192
#define OCL_  6144     // OC_*L_  (multiple of 32 -> MFMA K dim for stage B)
#define KS_   16       // k-split for stage B
#define KCH_  384      // OCL_/KS_
#define NT_   1564     // NP_/64 n-tiles
#define EPS_  1e-5f

typedef __attribute__((ext_vector_type(8))) short  bf16x8;
typedef __attribute__((ext_vector_type(4))) float  f32x4;

static __device__ __forceinline__ unsigned short f2bf(float x) {
    unsigned int u = __float_as_uint(x);
    unsigned int r = (u + 0x7FFFu + ((u >> 16) & 1u)) >> 16;
    return (unsigned short)r;
}

// ---------------- K1: fat kernel, two independent block roles ----------------
//  blocks [0, 1024)     : stage A  -> y_bf[b][6144] (bf16)
//  blocks [1024, 1408)  : W_fc [6144][200] fp32 -> Wt_bf [256][6144] bf16 (transposed, pad)
__global__ __launch_bounds__(256) void k1(
    const int* __restrict__ e1_idx, const int* __restrict__ r_idx,
    const float* __restrict__ E, const float* __restrict__ R,
    const float* __restrict__ W_fc1, const float* __restrict__ b_fc1,
    const float* __restrict__ W_fc,
    const float* __restrict__ bn0_g, const float* __restrict__ bn0_b,
    const float* __restrict__ bn0_m, const float* __restrict__ bn0_v,
    const float* __restrict__ bn1_g, const float* __restrict__ bn1_b,
    const float* __restrict__ bn1_m, const float* __restrict__ bn1_v,
    unsigned short* __restrict__ y_bf, unsigned short* __restrict__ Wt_bf)
{
    const int tid = threadIdx.x;
    const int bid = blockIdx.x;

    if (bid < B_) {
        // ---- stage A: x = bn0(E[e1]); k = s1*(R[r]@W_fc1+b_fc1); y = conv(x,k)+t1 ----
        __shared__ float x_lds[D_];
        __shared__ float r_lds[D_];
        __shared__ float k_lds[OC_ * FW_];
        __shared__ float s1_lds[OC_], t1_lds[OC_];

        const int b = bid;
        const float s0 = bn0_g[0] / sqrtf(bn0_v[0] + EPS_);
        const float c0 = bn0_b[0] - bn0_m[0] * s0;

        if (tid < D_) {
            x_lds[tid] = E[(long)e1_idx[b] * D_ + tid] * s0 + c0;
            r_lds[tid] = R[(long)r_idx[b] * D_ + tid];
        } else if (tid >= 224) {
            int o = tid - 224;
            float s1 = bn1_g[o] / sqrtf(bn1_v[o] + EPS_);
            s1_lds[o] = s1;
            t1_lds[o] = bn1_b[o] - bn1_m[o] * s1;
        }
        __syncthreads();

        for (int j = tid; j < OC_ * FW_; j += 256) {
            float acc = b_fc1[j];
            #pragma unroll 4
            for (int d = 0; d < D_; ++d)
                acc += r_lds[d] * W_fc1[d * (OC_ * FW_) + j];
            k_lds[j] = acc * s1_lds[j / FW_];
        }
        __syncthreads();

        unsigned short* yrow = y_bf + (long)b * OCL_;
        for (int idx = tid; idx < OCL_; idx += 256) {
            int o = idx / L_;
            int l = idx - o * L_;
            const float* kp = &k_lds[o * FW_];
            float acc = t1_lds[o];
            #pragma unroll
            for (int w = 0; w < FW_; ++w)
                acc += x_lds[l + w] * kp[w];
            yrow[idx] = f2bf(acc);
        }
    } else {
        // ---- W_fc transpose + bf16 convert: Wt_bf[d][k] = bf16(W_fc[k][d]), d<200 else 0 ----
        __shared__ float t_lds[64][65];
        const int wb = bid - B_;
        const int k0 = (wb % 96) * 64;      // 96 k-tiles of 64 over 6144
        const int d0 = (wb / 96) * 64;      // 4 d-tiles of 64 over 256
        const int c  = tid & 63;
        const int r4 = tid >> 6;
        #pragma unroll
        for (int i = 0; i < 16; ++i) {
            int row = i * 4 + r4;           // k within tile
            t_lds[row][c] = (d0 + c < D_) ? W_fc[(long)(k0 + row) * D_ + d0 + c] : 0.f;
        }
        __syncthreads();
        #pragma unroll
        for (int i = 0; i < 16; ++i) {
            int drow = i * 4 + r4;          // d within tile
            Wt_bf[(long)(d0 + drow) * OCL_ + k0 + c] = f2bf(t_lds[c][drow]);
        }
    }
}

// ---------------- kB: pre[ks][b][d] = partial( y[b,:] @ Wt[d,:] ), bf16 MFMA ----------------
__global__ __launch_bounds__(256) void kB(
    const unsigned short* __restrict__ y_bf, const unsigned short* __restrict__ Wt_bf,
    float* __restrict__ pre)
{
    const int wave = threadIdx.x >> 6;
    const int lane = threadIdx.x & 63;
    const int quad = lane >> 4;
    const int lc   = lane & 15;

    const int m0 = blockIdx.x * 128 + wave * 32;
    const int n0 = blockIdx.y * 64;
    const int kb = blockIdx.z * KCH_;

    f32x4 acc[2][4] = {};

    const short* a0p = (const short*)y_bf + (long)(m0 + lc) * OCL_ + kb + quad * 8;
    const short* a1p = a0p + 16 * OCL_;

    #pragma unroll
    for (int k0 = 0; k0 < KCH_; k0 += 32) {
        bf16x8 a0 = *(const bf16x8*)(a0p + k0);
        bf16x8 a1 = *(const bf16x8*)(a1p + k0);
        #pragma unroll
        for (int t = 0; t < 4; ++t) {
            bf16x8 bv = *(const bf16x8*)((const short*)Wt_bf
                         + (long)(n0 + t * 16 + lc) * OCL_ + kb + k0 + quad * 8);
            acc[0][t] = __builtin_amdgcn_mfma_f32_16x16x32_bf16(a0, bv, acc[0][t], 0, 0, 0);
            acc[1][t] = __builtin_amdgcn_mfma_f32_16x16x32_bf16(a1, bv, acc[1][t], 0, 0, 0);
        }
    }

    #pragma unroll
    for (int t = 0; t < 4; ++t) {
        int d = n0 + t * 16 + lc;
        if (d < KP_) {
            #pragma unroll
            for (int mi = 0; mi < 2; ++mi)
                #pragma unroll
                for (int r = 0; r < 4; ++r) {
                    int m = m0 + mi * 16 + quad * 4 + r;
                    pre[((long)blockIdx.z * B_ + m) * KP_ + d] = acc[mi][t][r];
                }
        }
    }
}

// ---------------- kB2: reduce splits + bias + bn2 + relu -> h_bf (bf16, K-padded) ----
__global__ __launch_bounds__(256) void kB2(
    const float* __restrict__ pre, const float* __restrict__ b_fc,
    const float* __restrict__ bn2_g, const float* __restrict__ bn2_b,
    const float* __restrict__ bn2_m, const float* __restrict__ bn2_v,
    unsigned short* __restrict__ h_bf)
{
    int id = blockIdx.x * 256 + threadIdx.x;
    if (id >= B_ * KP_) return;
    int b = id / KP_;
    int d = id - b * KP_;
    float h = 0.f;
    if (d < D_) {
        float s = 0.f;
        #pragma unroll
        for (int sp = 0; sp < KS_; ++sp)
            s += pre[(long)sp * B_ * KP_ + id];
        float s2 = bn2_g[d] / sqrtf(bn2_v[d] + EPS_);
        h = (s + b_fc[d] - bn2_m[d]) * s2 + bn2_b[d];
        h = fmaxf(h, 0.f);
    }
    h_bf[id] = f2bf(h);
}

// ---------------- kC: out[b][n] = sigmoid(h[b,:] . E[n,:] + bias[n]) ---------------
// MFMA 16x16x32 bf16. Wave tile 32m x 64n, block = 4 waves on m (128m x 64n).
// v3: (1) B tile staged straight from E fp32 (convert-in-kernel, E_bf pass deleted);
//     (2) chunked XCD swizzle: all 8 m-tiles of an n-tile land on ONE XCD -> the E
//     tile is fetched into that XCD's L2 once and reused 8x (was 8 XCDs x 1 use);
//     (3) swizzled LDS (c16^(row&7), write AND read) -> conflict-free ds_read_b128;
//     (4) epilogue transposes acc through LDS -> 256B-contiguous float4 stores.
__global__ __launch_bounds__(256) void kC(
    const unsigned short* __restrict__ h_bf, const float* __restrict__ E,
    const float* __restrict__ bias, float* __restrict__ out)
{
    __shared__ short smem[64 * 256];   // 32 KB: phase1 = swizzled B tile; phase2 = f32 epilogue

    const int tid  = threadIdx.x;
    const int wave = tid >> 6;
    const int lane = tid & 63;
    const int quad = lane >> 4;
    const int lc   = lane & 15;

    // chunked XCD swizzle over 12512 blocks (dispatch: xcd = bid % 8)
    const int bid = blockIdx.x;
    const int g   = (bid & 7) * NT_ + (bid >> 3);   // bijective; contiguous per XCD
    const int m0  = (g & 7) * 128 + wave * 32;
    const int n0  = (g >> 3) * 64;

    // ---- stage B tile: rows n0..n0+63 of E (fp32) -> bf16 LDS, swizzled, zero-pad ----
    {
        #pragma unroll
        for (int i = 0; i < 14; ++i) {
            int u   = tid + i * 256;          // 0..3583 = 64 rows x 56 8B-slots
            int row = u / 56;
            int s8  = u - row * 56;           // 4-col group
            int n   = n0 + row;
            ushort4 o = {0, 0, 0, 0};
            if (n < N_ && s8 < 50) {          // cols s8*4..s8*4+3 < 200
                float4 v = *(const float4*)&E[(long)n * D_ + s8 * 4];
                o.x = f2bf(v.x); o.y = f2bf(v.y); o.z = f2bf(v.z); o.w = f2bf(v.w);
            }
            int c16 = s8 >> 1, half = s8 & 1;
            *(ushort4*)&smem[row * 256 + ((c16 ^ (row & 7)) << 3) + half * 4] = o;
        }
    }
    __syncthreads();

    f32x4 acc[2][4] = {};

    const short* hbase0 = (const short*)h_bf + (long)(m0 + lc) * KP_ + quad * 8;
    const short* hbase1 = hbase0 + 16 * KP_;

    #pragma unroll
    for (int k0 = 0; k0 < KP_; k0 += 32) {
        bf16x8 a0 = *(const bf16x8*)(hbase0 + k0);
        bf16x8 a1 = *(const bf16x8*)(hbase1 + k0);
        const int cbase = (k0 >> 3) + quad;
        #pragma unroll
        for (int t = 0; t < 4; ++t) {
            int row = t * 16 + lc;
            int c   = cbase ^ (row & 7);
            bf16x8 bv = *(const bf16x8*)&smem[row * 256 + c * 8];
            acc[0][t] = __builtin_amdgcn_mfma_f32_16x16x32_bf16(a0, bv, acc[0][t], 0, 0, 0);
            acc[1][t] = __builtin_amdgcn_mfma_f32_16x16x32_bf16(a1, bv, acc[1][t], 0, 0, 0);
        }
    }

    // ---- epilogue: acc (+bias) -> LDS (wave-private 8KB) -> coalesced 256B-row stores ----
    __syncthreads();                       // all waves done reading B tile
    float* fw = (float*)smem + wave * 2048;   // [32 rows][64 cols] f32

    #pragma unroll
    for (int t = 0; t < 4; ++t) {
        int n = n0 + t * 16 + lc;
        float bv = (n < N_) ? bias[n] : 0.f;
        #pragma unroll
        for (int mi = 0; mi < 2; ++mi)
            #pragma unroll
            for (int r = 0; r < 4; ++r) {
                int rl = mi * 16 + quad * 4 + r;
                fw[rl * 64 + t * 16 + lc] = acc[mi][t][r] + bv;
            }
    }
    // wave-private region: no second barrier needed (compiler inserts lgkmcnt)

    #pragma unroll
    for (int j = 0; j < 8; ++j) {
        int u  = lane + j * 64;            // 0..511 float4 units in this wave's tile
        int rl = u >> 4;                   // local row 0..31
        int c4 = u & 15;                   // float4 col 0..15
        int n  = n0 + c4 * 4;
        if (n < N_) {                      // N_ % 4 == 0 -> all-or-nothing per float4
            float4 v = *(const float4*)&fw[rl * 64 + c4 * 4];
            float4 o;
            o.x = 1.f / (1.f + __expf(-v.x));
            o.y = 1.f / (1.f + __expf(-v.y));
            o.z = 1.f / (1.f + __expf(-v.z));
            o.w = 1.f / (1.f + __expf(-v.w));
            *(float4*)&out[(long)(m0 + rl) * N_ + n] = o;
        }
    }
}

extern "C" void kernel_launch(void* const* d_in, const int* in_sizes, int n_in,
                              void* d_out, int out_size, void* d_ws, size_t ws_size,
                              hipStream_t stream) {
    const int*   e1_idx = (const int*)d_in[0];
    const int*   r_idx  = (const int*)d_in[1];
    const float* E      = (const float*)d_in[2];
    const float* R      = (const float*)d_in[3];
    const float* W_fc   = (const float*)d_in[4];
    const float* b_fc   = (const float*)d_in[5];
    const float* W_fc1  = (const float*)d_in[6];
    const float* b_fc1  = (const float*)d_in[7];
    const float* bn0_g  = (const float*)d_in[8];
    const float* bn0_b  = (const float*)d_in[9];
    const float* bn0_m  = (const float*)d_in[10];
    const float* bn0_v  = (const float*)d_in[11];
    const float* bn1_g  = (const float*)d_in[12];
    const float* bn1_b  = (const float*)d_in[13];
    const float* bn1_m  = (const float*)d_in[14];
    const float* bn1_v  = (const float*)d_in[15];
    const float* bn2_g  = (const float*)d_in[16];
    const float* bn2_b  = (const float*)d_in[17];
    const float* bn2_m  = (const float*)d_in[18];
    const float* bn2_v  = (const float*)d_in[19];
    const float* bias   = (const float*)d_in[20];
    float* out = (float*)d_out;

    // ws layout:
    //   y_bf  @ 0          : 1024*6144*2   = 12,582,912
    //   pre   @ 12,582,912 : 16*1024*224*4 = 14,680,064   (ends 27,262,976)
    //   Wt_bf @ 27,262,976 : 256*6144*2    =  3,145,728   (ends 30,408,704)
    //   h_bf  @ 44,843,008 : 1024*224*2    =    458,752   (ends 45,301,760)
    char* base = (char*)d_ws;
    unsigned short* y_bf  = (unsigned short*)(base);
    float*          pre   = (float*)(base + 12582912L);
    unsigned short* Wt_bf = (unsigned short*)(base + 27262976L);
    unsigned short* h_bf  = (unsigned short*)(base + 44843008L);

    k1<<<B_ + 384, 256, 0, stream>>>(e1_idx, r_idx, E, R, W_fc1, b_fc1, W_fc,
                                     bn0_g, bn0_b, bn0_m, bn0_v,
                                     bn1_g, bn1_b, bn1_m, bn1_v,
                                     y_bf, Wt_bf);
    kB<<<dim3(8, 4, KS_), 256, 0, stream>>>(y_bf, Wt_bf, pre);
    kB2<<<(B_ * KP_ + 255) / 256, 256, 0, stream>>>(pre, b_fc, bn2_g, bn2_b, bn2_m, bn2_v, h_bf);
    kC<<<8 * NT_, 256, 0, stream>>>(h_bf, E, bias, out);
}

// Round 4
// 640.576 us; speedup vs baseline: 1.1447x; 1.1447x over previous
//
#include <hip/hip_runtime.h>

#define B_    1024
#define N_    100000
#define NR_   500
#define D_    200
#define KP_   224      // D padded to multiple of 32 (MFMA K)
#define OC_   32
#define FW_   9
#define L_    192
#define OCL_  6144     // OC_*L_  (multiple of 32 -> MFMA K dim for stage B)
#define KS_   16       // k-split for stage B
#define KCH_  384      // OCL_/KS_
#define NT_   1563     // ceil(N_/64) n-tiles (1562*64=99968 < 100000 <= 1563*64)
#define EPS_  1e-5f

typedef __attribute__((ext_vector_type(8))) short  bf16x8;
typedef __attribute__((ext_vector_type(4))) float  f32x4;

static __device__ __forceinline__ unsigned short f2bf(float x) {
    unsigned int u = __float_as_uint(x);
    unsigned int r = (u + 0x7FFFu + ((u >> 16) & 1u)) >> 16;
    return (unsigned short)r;
}

// ---------------- K1: fat kernel, two independent block roles ----------------
//  blocks [0, 1024)     : stage A  -> y_bf[b][6144] (bf16)
//  blocks [1024, 1408)  : W_fc [6144][200] fp32 -> Wt_bf [256][6144] bf16 (transposed, pad)
__global__ __launch_bounds__(256) void k1(
    const int* __restrict__ e1_idx, const int* __restrict__ r_idx,
    const float* __restrict__ E, const float* __restrict__ R,
    const float* __restrict__ W_fc1, const float* __restrict__ b_fc1,
    const float* __restrict__ W_fc,
    const float* __restrict__ bn0_g, const float* __restrict__ bn0_b,
    const float* __restrict__ bn0_m, const float* __restrict__ bn0_v,
    const float* __restrict__ bn1_g, const float* __restrict__ bn1_b,
    const float* __restrict__ bn1_m, const float* __restrict__ bn1_v,
    unsigned short* __restrict__ y_bf, unsigned short* __restrict__ Wt_bf)
{
    const int tid = threadIdx.x;
    const int bid = blockIdx.x;

    if (bid < B_) {
        // ---- stage A: x = bn0(E[e1]); k = s1*(R[r]@W_fc1+b_fc1); y = conv(x,k)+t1 ----
        __shared__ float x_lds[D_];
        __shared__ float r_lds[D_];
        __shared__ float k_lds[OC_ * FW_];
        __shared__ float s1_lds[OC_], t1_lds[OC_];

        const int b = bid;
        const float s0 = bn0_g[0] / sqrtf(bn0_v[0] + EPS_);
        const float c0 = bn0_b[0] - bn0_m[0] * s0;

        if (tid < D_) {
            x_lds[tid] = E[(long)e1_idx[b] * D_ + tid] * s0 + c0;
            r_lds[tid] = R[(long)r_idx[b] * D_ + tid];
        } else if (tid >= 224) {
            int o = tid - 224;
            float s1 = bn1_g[o] / sqrtf(bn1_v[o] + EPS_);
            s1_lds[o] = s1;
            t1_lds[o] = bn1_b[o] - bn1_m[o] * s1;
        }
        __syncthreads();

        for (int j = tid; j < OC_ * FW_; j += 256) {
            float acc = b_fc1[j];
            #pragma unroll 4
            for (int d = 0; d < D_; ++d)
                acc += r_lds[d] * W_fc1[d * (OC_ * FW_) + j];
            k_lds[j] = acc * s1_lds[j / FW_];
        }
        __syncthreads();

        unsigned short* yrow = y_bf + (long)b * OCL_;
        for (int idx = tid; idx < OCL_; idx += 256) {
            int o = idx / L_;
            int l = idx - o * L_;
            const float* kp = &k_lds[o * FW_];
            float acc = t1_lds[o];
            #pragma unroll
            for (int w = 0; w < FW_; ++w)
                acc += x_lds[l + w] * kp[w];
            yrow[idx] = f2bf(acc);
        }
    } else {
        // ---- W_fc transpose + bf16 convert: Wt_bf[d][k] = bf16(W_fc[k][d]), d<200 else 0 ----
        __shared__ float t_lds[64][65];
        const int wb = bid - B_;
        const int k0 = (wb % 96) * 64;      // 96 k-tiles of 64 over 6144
        const int d0 = (wb / 96) * 64;      // 4 d-tiles of 64 over 256
        const int c  = tid & 63;
        const int r4 = tid >> 6;
        #pragma unroll
        for (int i = 0; i < 16; ++i) {
            int row = i * 4 + r4;           // k within tile
            t_lds[row][c] = (d0 + c < D_) ? W_fc[(long)(k0 + row) * D_ + d0 + c] : 0.f;
        }
        __syncthreads();
        #pragma unroll
        for (int i = 0; i < 16; ++i) {
            int drow = i * 4 + r4;          // d within tile
            Wt_bf[(long)(d0 + drow) * OCL_ + k0 + c] = f2bf(t_lds[c][drow]);
        }
    }
}

// ---------------- kB: pre[ks][b][d] = partial( y[b,:] @ Wt[d,:] ), bf16 MFMA ----------------
__global__ __launch_bounds__(256) void kB(
    const unsigned short* __restrict__ y_bf, const unsigned short* __restrict__ Wt_bf,
    float* __restrict__ pre)
{
    const int wave = threadIdx.x >> 6;
    const int lane = threadIdx.x & 63;
    const int quad = lane >> 4;
    const int lc   = lane & 15;

    const int m0 = blockIdx.x * 128 + wave * 32;
    const int n0 = blockIdx.y * 64;
    const int kb = blockIdx.z * KCH_;

    f32x4 acc[2][4] = {};

    const short* a0p = (const short*)y_bf + (long)(m0 + lc) * OCL_ + kb + quad * 8;
    const short* a1p = a0p + 16 * OCL_;

    #pragma unroll
    for (int k0 = 0; k0 < KCH_; k0 += 32) {
        bf16x8 a0 = *(const bf16x8*)(a0p + k0);
        bf16x8 a1 = *(const bf16x8*)(a1p + k0);
        #pragma unroll
        for (int t = 0; t < 4; ++t) {
            bf16x8 bv = *(const bf16x8*)((const short*)Wt_bf
                         + (long)(n0 + t * 16 + lc) * OCL_ + kb + k0 + quad * 8);
            acc[0][t] = __builtin_amdgcn_mfma_f32_16x16x32_bf16(a0, bv, acc[0][t], 0, 0, 0);
            acc[1][t] = __builtin_amdgcn_mfma_f32_16x16x32_bf16(a1, bv, acc[1][t], 0, 0, 0);
        }
    }

    #pragma unroll
    for (int t = 0; t < 4; ++t) {
        int d = n0 + t * 16 + lc;
        if (d < KP_) {
            #pragma unroll
            for (int mi = 0; mi < 2; ++mi)
                #pragma unroll
                for (int r = 0; r < 4; ++r) {
                    int m = m0 + mi * 16 + quad * 4 + r;
                    pre[((long)blockIdx.z * B_ + m) * KP_ + d] = acc[mi][t][r];
                }
        }
    }
}

// ---------------- kB2: reduce splits + bias + bn2 + relu -> h_bf (bf16, K-padded) ----
__global__ __launch_bounds__(256) void kB2(
    const float* __restrict__ pre, const float* __restrict__ b_fc,
    const float* __restrict__ bn2_g, const float* __restrict__ bn2_b,
    const float* __restrict__ bn2_m, const float* __restrict__ bn2_v,
    unsigned short* __restrict__ h_bf)
{
    int id = blockIdx.x * 256 + threadIdx.x;
    if (id >= B_ * KP_) return;
    int b = id / KP_;
    int d = id - b * KP_;
    float h = 0.f;
    if (d < D_) {
        float s = 0.f;
        #pragma unroll
        for (int sp = 0; sp < KS_; ++sp)
            s += pre[(long)sp * B_ * KP_ + id];
        float s2 = bn2_g[d] / sqrtf(bn2_v[d] + EPS_);
        h = (s + b_fc[d] - bn2_m[d]) * s2 + bn2_b[d];
        h = fmaxf(h, 0.f);
    }
    h_bf[id] = f2bf(h);
}

// ---------------- kC: out[b][n] = sigmoid(h[b,:] . E[n,:] + bias[n]) ---------------
// v4: ONE block per 64-row n-tile (grid 1563). Block stages its E tile (fp32->bf16,
// swizzled LDS) ONCE, then loops over all 8 m-tiles of 128 rows: A-frags from
// L2-hot h_bf, 56 MFMA/wave, wave-private epilogue in a SEPARATE LDS region
// (stride 68 pads the old 4-way write conflict away), coalesced float4 stores.
// Single barrier per block; waves drift -> natural MFMA/VALU/store overlap.
__global__ __launch_bounds__(256) void kC(
    const unsigned short* __restrict__ h_bf, const float* __restrict__ E,
    const float* __restrict__ bias, float* __restrict__ out)
{
    __shared__ short smemB[64 * 256];       // 32 KB swizzled bf16 B tile (64n x 224k)
    __shared__ float smemE[4][32 * 68];     // 34 KB epilogue scratch, wave-private slices

    const int tid  = threadIdx.x;
    const int wave = tid >> 6;
    const int lane = tid & 63;
    const int quad = lane >> 4;
    const int lc   = lane & 15;
    const int n0   = blockIdx.x * 64;

    // ---- stage B tile: rows n0..n0+63 of E (fp32) -> bf16 LDS, swizzled, zero-pad ----
    #pragma unroll
    for (int i = 0; i < 14; ++i) {
        int u   = tid + i * 256;          // 0..3583 = 64 rows x 56 8B-slots
        int row = u / 56;
        int s8  = u - row * 56;
        int n   = n0 + row;
        ushort4 o = {0, 0, 0, 0};
        if (n < N_ && s8 < 50) {          // cols s8*4..s8*4+3 < 200
            float4 v = *(const float4*)&E[(long)n * D_ + s8 * 4];
            o.x = f2bf(v.x); o.y = f2bf(v.y); o.z = f2bf(v.z); o.w = f2bf(v.w);
        }
        int c16 = s8 >> 1, half = s8 & 1;
        *(ushort4*)&smemB[row * 256 + ((c16 ^ (row & 7)) << 3) + half * 4] = o;
    }
    __syncthreads();

    float bv[4];
    #pragma unroll
    for (int t = 0; t < 4; ++t) {
        int n = n0 + t * 16 + lc;
        bv[t] = (n < N_) ? bias[n] : 0.f;
    }

    float* fw = smemE[wave];

    for (int mi = 0; mi < 8; ++mi) {
        const int m0 = mi * 128 + wave * 32;

        // A fragments (32 m-rows x 224 k) from h_bf -- L2-resident (448 KB total)
        const short* hb = (const short*)h_bf + (long)(m0 + lc) * KP_ + quad * 8;
        bf16x8 a0v[7], a1v[7];
        #pragma unroll
        for (int kk = 0; kk < 7; ++kk) {
            a0v[kk] = *(const bf16x8*)(hb + kk * 32);
            a1v[kk] = *(const bf16x8*)(hb + 16 * KP_ + kk * 32);
        }

        f32x4 acc[2][4] = {};
        #pragma unroll
        for (int kk = 0; kk < 7; ++kk) {
            const int cbase = kk * 4 + quad;
            #pragma unroll
            for (int t = 0; t < 4; ++t) {
                int row = t * 16 + lc;
                int c   = cbase ^ (row & 7);
                bf16x8 bvv = *(const bf16x8*)&smemB[row * 256 + c * 8];
                acc[0][t] = __builtin_amdgcn_mfma_f32_16x16x32_bf16(a0v[kk], bvv, acc[0][t], 0, 0, 0);
                acc[1][t] = __builtin_amdgcn_mfma_f32_16x16x32_bf16(a1v[kk], bvv, acc[1][t], 0, 0, 0);
            }
        }

        // ---- epilogue (wave-private): acc+bias -> fw -> sigmoid -> 256B-row stores ----
        #pragma unroll
        for (int t = 0; t < 4; ++t)
            #pragma unroll
            for (int mii = 0; mii < 2; ++mii)
                #pragma unroll
                for (int r = 0; r < 4; ++r) {
                    int rl = mii * 16 + quad * 4 + r;
                    fw[rl * 68 + t * 16 + lc] = acc[mii][t][r] + bv[t];
                }
        // wave-private region: compiler inserts lgkmcnt ordering, no barrier needed

        #pragma unroll
        for (int j = 0; j < 8; ++j) {
            int u  = lane + j * 64;        // 0..511 float4 units in this wave's tile
            int rl = u >> 4;               // local row 0..31
            int c4 = u & 15;               // float4 col 0..15
            int n  = n0 + c4 * 4;
            if (n < N_) {                  // N_ % 4 == 0 -> all-or-nothing per float4
                float4 v = *(const float4*)&fw[rl * 68 + c4 * 4];
                float4 o;
                o.x = 1.f / (1.f + __expf(-v.x));
                o.y = 1.f / (1.f + __expf(-v.y));
                o.z = 1.f / (1.f + __expf(-v.z));
                o.w = 1.f / (1.f + __expf(-v.w));
                *(float4*)&out[(long)(m0 + rl) * N_ + n] = o;
            }
        }
    }
}

extern "C" void kernel_launch(void* const* d_in, const int* in_sizes, int n_in,
                              void* d_out, int out_size, void* d_ws, size_t ws_size,
                              hipStream_t stream) {
    const int*   e1_idx = (const int*)d_in[0];
    const int*   r_idx  = (const int*)d_in[1];
    const float* E      = (const float*)d_in[2];
    const float* R      = (const float*)d_in[3];
    const float* W_fc   = (const float*)d_in[4];
    const float* b_fc   = (const float*)d_in[5];
    const float* W_fc1  = (const float*)d_in[6];
    const float* b_fc1  = (const float*)d_in[7];
    const float* bn0_g  = (const float*)d_in[8];
    const float* bn0_b  = (const float*)d_in[9];
    const float* bn0_m  = (const float*)d_in[10];
    const float* bn0_v  = (const float*)d_in[11];
    const float* bn1_g  = (const float*)d_in[12];
    const float* bn1_b  = (const float*)d_in[13];
    const float* bn1_m  = (const float*)d_in[14];
    const float* bn1_v  = (const float*)d_in[15];
    const float* bn2_g  = (const float*)d_in[16];
    const float* bn2_b  = (const float*)d_in[17];
    const float* bn2_m  = (const float*)d_in[18];
    const float* bn2_v  = (const float*)d_in[19];
    const float* bias   = (const float*)d_in[20];
    float* out = (float*)d_out;

    // ws layout:
    //   y_bf  @ 0          : 1024*6144*2   = 12,582,912
    //   pre   @ 12,582,912 : 16*1024*224*4 = 14,680,064   (ends 27,262,976)
    //   Wt_bf @ 27,262,976 : 256*6144*2    =  3,145,728   (ends 30,408,704)
    //   h_bf  @ 44,843,008 : 1024*224*2    =    458,752   (ends 45,301,760)
    char* base = (char*)d_ws;
    unsigned short* y_bf  = (unsigned short*)(base);
    float*          pre   = (float*)(base + 12582912L);
    unsigned short* Wt_bf = (unsigned short*)(base + 27262976L);
    unsigned short* h_bf  = (unsigned short*)(base + 44843008L);

    k1<<<B_ + 384, 256, 0, stream>>>(e1_idx, r_idx, E, R, W_fc1, b_fc1, W_fc,
                                     bn0_g, bn0_b, bn0_m, bn0_v,
                                     bn1_g, bn1_b, bn1_m, bn1_v,
                                     y_bf, Wt_bf);
    kB<<<dim3(8, 4, KS_), 256, 0, stream>>>(y_bf, Wt_bf, pre);
    kB2<<<(B_ * KP_ + 255) / 256, 256, 0, stream>>>(pre, b_fc, bn2_g, bn2_b, bn2_m, bn2_v, h_bf);
    kC<<<NT_, 256, 0, stream>>>(h_bf, E, bias, out);
}